// Round 16
// baseline (181.220 us; speedup 1.0000x reference)
//
#include <hip/hip_runtime.h>
#include <cstdint>
#include <cstddef>

#define B_ 4
#define C_ 256
#define N_ 4096

typedef __attribute__((ext_vector_type(8))) short s8v;    // 8 bf16 (4 VGPRs) MFMA A/B frag
typedef __attribute__((ext_vector_type(4))) float f4v;    // 16x16 MFMA C/D frag
typedef __attribute__((ext_vector_type(16))) float f16v;  // 32x32 MFMA C/D frag
typedef long long i64f;                                   // 8 fp8 (2 VGPRs) MFMA A/B frag

#if defined(__has_builtin)
#if __has_builtin(__builtin_amdgcn_exp2f)
#define EXP2(x) __builtin_amdgcn_exp2f(x)
#endif
#endif
#ifndef EXP2
#define EXP2(x) exp2f(x)
#endif

// scheduling fence: no instruction may be reordered across (pins prefetch issue)
#define SCHED_FENCE() __builtin_amdgcn_sched_barrier(0)

__device__ __forceinline__ unsigned short f2bf(float f) {
  unsigned int u = __builtin_bit_cast(unsigned int, f);
  return (unsigned short)((u + 0x7FFFu + ((u >> 16) & 1u)) >> 16);  // RNE
}

__device__ __forceinline__ float bf2f(unsigned short u) {
  return __builtin_bit_cast(float, (unsigned)u << 16);
}

__device__ __forceinline__ f16v zf16() {
  f16v z;
#pragma unroll
  for (int i = 0; i < 16; ++i) z[i] = 0.f;
  return z;
}

// Layouts:
//  16x16 B-frag blocked bf16 (aS LDS tile): flat = ((n>>4)*32 + (c>>3))*128 + (n&15)*8 + (c&7)
//  qB/kB FP8 e4m3 (32x32x16 fp8 frags, BYTE units): byte = frag_idx*512 + l*8
//    q frag_idx = ((b*128 + n32)*16 + cs) ; k frag_idx = ((b*128 + kg)*16 + cs)
//  vB FP8 e4m3 (BYTE units): byte = (((b*8 + cg)*256 + ks)*64 + l)*8 + e
//  P LDS fp8 (64 rows, 2 rg): byte = k8*512 + l31*8 + klow (+256 for rg=1)
//  NOTE: sqrt(C^-0.5 * log2e) folded into BOTH wq and wk (fp8 dynamic range).

// ---------------- K1: BatchNorm statistics ----------------
__global__ __launch_bounds__(256) void bn_stats(const float* __restrict__ x,
                                                float* __restrict__ mean,
                                                float* __restrict__ rstd) {
  int c = blockIdx.x, t = threadIdx.x;
  float s = 0.f, s2 = 0.f;
  for (int b = 0; b < B_; ++b) {
    const float* p = x + ((size_t)b * C_ + c) * N_;
    for (int n = t * 4; n < N_; n += 1024) {
      float4 v = *(const float4*)(p + n);
      s += (v.x + v.y) + (v.z + v.w);
      s2 += (v.x * v.x + v.y * v.y) + (v.z * v.z + v.w * v.w);
    }
  }
  __shared__ float rs[256], rs2[256];
  rs[t] = s; rs2[t] = s2; __syncthreads();
  for (int off = 128; off > 0; off >>= 1) {
    if (t < off) { rs[t] += rs[t + off]; rs2[t] += rs2[t + off]; }
    __syncthreads();
  }
  if (t == 0) {
    float m = rs[0] * (1.f / 16384.f);
    float v = rs2[0] * (1.f / 16384.f) - m * m;
    mean[c] = m; rstd[c] = rsqrtf(v + 1e-5f);
  }
}

// ---------------- K2: fold BN + split QK scale into weights ----------------
__global__ __launch_bounds__(256) void prep(
    const float* __restrict__ wq, const float* __restrict__ bq,
    const float* __restrict__ wk, const float* __restrict__ bk,
    const float* __restrict__ wv, const float* __restrict__ bv,
    const float* __restrict__ wp,
    const float* __restrict__ gamma, const float* __restrict__ beta,
    const float* __restrict__ mean, const float* __restrict__ rstd,
    unsigned short* __restrict__ wqb, unsigned short* __restrict__ wkb,
    unsigned short* __restrict__ wvb, unsigned short* __restrict__ wpb,
    float* __restrict__ beq, float* __restrict__ bek, float* __restrict__ bev) {
  const float SQ = 0.300280605f;   // sqrt(C^-0.5 * log2(e)); applied to BOTH q and k
  int o = blockIdx.x, c = threadIdx.x;
  float a = gamma[c] * rstd[c];
  float d = beta[c] - mean[c] * a;
  float wqv = wq[o * C_ + c], wkv = wk[o * C_ + c], wvv = wv[o * C_ + c];
  wqb[o * C_ + c] = f2bf(wqv * a * SQ);
  wkb[o * C_ + c] = f2bf(wkv * a * SQ);
  wvb[o * C_ + c] = f2bf(wvv * a);
  wpb[o * C_ + c] = f2bf(wp[o * C_ + c]);
  __shared__ float r0[256], r1[256], r2[256];
  r0[c] = wqv * d; r1[c] = wkv * d; r2[c] = wvv * d; __syncthreads();
  for (int off = 128; off > 0; off >>= 1) {
    if (c < off) { r0[c] += r0[c + off]; r1[c] += r1[c + off]; r2[c] += r2[c + off]; }
    __syncthreads();
  }
  if (c == 0) {
    beq[o] = (bq[o] + r0[0]) * SQ;
    bek[o] = (bk[o] + r1[0]) * SQ;
    bev[o] = bv[o] + r2[0];
  }
}

// ---------------- K3: fused x-convert + QKV GEMM — stage x ONCE, loop all 4 oblks ----------------
// r14 grid was (N/64, 4, B): blockIdx.y = oblk, but x-staging is oblk-independent,
// so every 64 KB x-tile was read from HBM and staged into LDS FOUR times (256 MB
// of x traffic). Fix: grid (N/64, 1, B) = 256 blocks; stage x once into Ls (kept
// intact), loop oblk=0..3 internally with a SEPARATE 9 KB repack buffer Lr.
// x HBM reads /4, staging instructions /4; same MFMA/store volume. LDS 43 KB.
__global__ __launch_bounds__(256) void qkv(
    const float* __restrict__ x,
    const unsigned short* __restrict__ wqb, const unsigned short* __restrict__ wkb,
    const unsigned short* __restrict__ wvb,
    const float* __restrict__ beq, const float* __restrict__ bek,
    const float* __restrict__ bev,
    unsigned char* __restrict__ qB, unsigned char* __restrict__ kB,
    unsigned char* __restrict__ vB) {
  int b = blockIdx.z, n0 = blockIdx.x * 64;
  int tid = threadIdx.x, w = tid >> 6, l = tid & 63, quad = l >> 4, lq = l & 15;

  __shared__ unsigned short Ls[64][264];   // 33.8 KB x tile [n][c] — persistent
  __shared__ unsigned short Lr[64][72];    // 9.2 KB repack buffer

  // ---- stage x -> Ls (ONCE) ----
  {
    int cw = tid >> 6, nl = tid & 63;
    const float* xp = x + ((size_t)b * C_ + cw * 64) * N_ + n0 + nl;
#pragma unroll
    for (int i = 0; i < 32; ++i) {
      float f0 = xp[(size_t)(2 * i) * N_];
      float f1 = xp[(size_t)(2 * i + 1) * N_];
      unsigned pk = (unsigned)f2bf(f0) | ((unsigned)f2bf(f1) << 16);
      *(unsigned*)(&Ls[nl][cw * 64 + 2 * i]) = pk;
    }
  }
  __syncthreads();

  for (int oblk = 0; oblk < 4; ++oblk) {
    int obase = oblk * 64;
    int orow = obase + w * 16 + lq;

    f4v aq[4], ak[4], av[4];
#pragma unroll
    for (int nt = 0; nt < 4; ++nt) {
      aq[nt] = (f4v){0.f, 0.f, 0.f, 0.f};
      ak[nt] = (f4v){0.f, 0.f, 0.f, 0.f};
      av[nt] = (f4v){0.f, 0.f, 0.f, 0.f};
    }

#pragma unroll
    for (int kk = 0; kk < 8; ++kk) {
      s8v afq = *(const s8v*)(wqb + (size_t)orow * C_ + kk * 32 + quad * 8);
      s8v afk = *(const s8v*)(wkb + (size_t)orow * C_ + kk * 32 + quad * 8);
      s8v afv = *(const s8v*)(wvb + (size_t)orow * C_ + kk * 32 + quad * 8);
#pragma unroll
      for (int nt = 0; nt < 4; ++nt) {
        s8v bf = *(const s8v*)(&Ls[nt * 16 + lq][kk * 32 + quad * 8]);
        aq[nt] = __builtin_amdgcn_mfma_f32_16x16x32_bf16(afq, bf, aq[nt], 0, 0, 0);
        ak[nt] = __builtin_amdgcn_mfma_f32_16x16x32_bf16(afk, bf, ak[nt], 0, 0, 0);
        av[nt] = __builtin_amdgcn_mfma_f32_16x16x32_bf16(afv, bf, av[nt], 0, 0, 0);
      }
    }

    // pass 1: q -> qB ; pass 2: k -> kB   (stage [n][c] bf16 in Lr; gather; cvt FP8)
    for (int pass = 0; pass < 2; ++pass) {
      const f4v* acc = (pass == 0) ? aq : ak;
      const float* BE = (pass == 0) ? beq : bek;
      int ob4 = obase + w * 16 + quad * 4;
      float b0 = BE[ob4], b1 = BE[ob4 + 1], b2 = BE[ob4 + 2], b3 = BE[ob4 + 3];
      __syncthreads();   // Lr free (previous pass / previous oblk gathers done)
#pragma unroll
      for (int nt = 0; nt < 4; ++nt) {
        unsigned lo = (unsigned)f2bf(acc[nt][0] + b0) | ((unsigned)f2bf(acc[nt][1] + b1) << 16);
        unsigned hi = (unsigned)f2bf(acc[nt][2] + b2) | ((unsigned)f2bf(acc[nt][3] + b3) << 16);
        uint2 pr; pr.x = lo; pr.y = hi;
        *(uint2*)(&Lr[nt * 16 + lq][w * 16 + quad * 4]) = pr;
      }
      __syncthreads();
      {
        unsigned char* dp = (pass == 0) ? qB : kB;
#pragma unroll
        for (int ii = 0; ii < 2; ++ii) {
          int i = tid + ii * 256;
          int g = i >> 8, cs = (i >> 6) & 3, ll = i & 63;
          s8v vv = *(const s8v*)(&Lr[g * 32 + (ll & 31)][cs * 16 + ((ll >> 5) << 3)]);
          unsigned w0 = (unsigned)__builtin_amdgcn_cvt_pk_fp8_f32(
              bf2f((unsigned short)vv[0]), bf2f((unsigned short)vv[1]), 0, false);
          w0 = (unsigned)__builtin_amdgcn_cvt_pk_fp8_f32(
              bf2f((unsigned short)vv[2]), bf2f((unsigned short)vv[3]), (int)w0, true);
          unsigned w1 = (unsigned)__builtin_amdgcn_cvt_pk_fp8_f32(
              bf2f((unsigned short)vv[4]), bf2f((unsigned short)vv[5]), 0, false);
          w1 = (unsigned)__builtin_amdgcn_cvt_pk_fp8_f32(
              bf2f((unsigned short)vv[6]), bf2f((unsigned short)vv[7]), (int)w1, true);
          uint2 pr; pr.x = w0; pr.y = w1;
          size_t dst = ((((size_t)b * 128 + (n0 >> 5) + g) * 16 + (obase >> 4) + cs) * 64 + ll) * 8;
          *(uint2*)(dp + dst) = pr;
        }
      }
    }

    // pass 3: v (stage [c][n] bf16 in Lr; gather 32x32 A-frag; cvt FP8)
    __syncthreads();   // Lr free (k-pass gathers done)
#pragma unroll
    for (int nt = 0; nt < 4; ++nt)
#pragma unroll
      for (int r = 0; r < 4; ++r) {
        int o_ = obase + w * 16 + quad * 4 + r;
        Lr[w * 16 + quad * 4 + r][nt * 16 + lq] = f2bf(av[nt][r] + bev[o_]);
      }
    __syncthreads();
    {
#pragma unroll
      for (int ii = 0; ii < 2; ++ii) {
        int i = tid + ii * 256;
        int g = i >> 8, ks = (i >> 6) & 3, ll = i & 63;
        s8v vv = *(const s8v*)(&Lr[g * 32 + (ll & 31)][ks * 16 + ((ll >> 5) << 3)]);
        unsigned w0 = (unsigned)__builtin_amdgcn_cvt_pk_fp8_f32(
            bf2f((unsigned short)vv[0]), bf2f((unsigned short)vv[1]), 0, false);
        w0 = (unsigned)__builtin_amdgcn_cvt_pk_fp8_f32(
            bf2f((unsigned short)vv[2]), bf2f((unsigned short)vv[3]), (int)w0, true);
        unsigned w1 = (unsigned)__builtin_amdgcn_cvt_pk_fp8_f32(
            bf2f((unsigned short)vv[4]), bf2f((unsigned short)vv[5]), 0, false);
        w1 = (unsigned)__builtin_amdgcn_cvt_pk_fp8_f32(
            bf2f((unsigned short)vv[6]), bf2f((unsigned short)vv[7]), (int)w1, true);
        uint2 pr; pr.x = w0; pr.y = w1;
        size_t dst = ((((size_t)b * 8 + (obase >> 5) + g) * 256 + (n0 >> 4) + ks) * 64 + ll) * 8;
        *(uint2*)(vB + dst) = pr;
      }
    }
  }
}

// ---------------- K4: FMHA — full-FP8 operands: Q resident in regs, no Q LDS ----------------
// (byte-identical to the round-14 passing kernel: 70.9 us, absmax 0.031)
__global__ __launch_bounds__(512, 2) void attn(
    const unsigned char* __restrict__ qB, const unsigned char* __restrict__ kB,
    const unsigned char* __restrict__ vB,
    const unsigned short* __restrict__ wpb, const float* __restrict__ bp,
    const float* __restrict__ x, float* __restrict__ out) {
  int id = blockIdx.x;                       // id&7 = XCD (2 XCDs per batch)
  int b = (id & 7) >> 1;
  int i0 = (((id >> 3) << 1) | (id & 1)) << 6;   // 64 q-rows per block
  int tid = threadIdx.x, w = tid >> 6, l = tid & 63;
  int lh = l >> 5, l31 = l & 31;

  __shared__ unsigned char Ps[2][16384];     // 2 x 16 KB P tiles (fp8)
  __shared__ unsigned short aS[16384];       // 32 KB attn-out tile (bf16, proj input)
  __shared__ float Lw[8][2][32];

  // Q resident in registers: 32 fp8 B-frags (64 VGPR), loaded once from L2.
  i64f qf[2][16];
  {
    const unsigned char* qp = qB + (((size_t)b * 64 + (i0 >> 6)) * 32) * 512 + (size_t)l * 8;
#pragma unroll
    for (int rg = 0; rg < 2; ++rg)
#pragma unroll
      for (int cs = 0; cs < 16; ++cs)
        qf[rg][cs] = *(const i64f*)(qp + (size_t)(rg * 16 + cs) * 512);
  }

  // K (fp8): wave w owns key32-group w of each chunk; advance 8 groups = 65536 B/chunk
  const unsigned char* kp = kB + (((size_t)b * 128 + w) * 16) * 512 + (size_t)l * 8;
  // V (fp8): wave w owns channel-group w; frag ks at +ks*512 B
  const unsigned char* vp = vB + (((size_t)b * 8 + w) * 256) * 512 + (size_t)l * 8;

  // prologue: kf for chunk 0 (fp8: 16 x 8 B = 32 VGPR)
  i64f kf[16];
#pragma unroll
  for (int cs = 0; cs < 16; ++cs) kf[cs] = *(const i64f*)(kp + cs * 512);
  SCHED_FENCE();

  f16v O0 = zf16(), O1 = zf16();   // [rg] channels w*32+chl, rows i0+rg*32+l31
  float ls0 = 0.f, ls1 = 0.f;

  for (int t = 0; t < 16; ++t) {
    // ---- vf prefetch for THIS chunk ----
    i64f vf[16];
#pragma unroll
    for (int ks = 0; ks < 16; ++ks) vf[ks] = *(const i64f*)(vp + ks * 512);
    SCHED_FENCE();
    // ---- S phase: fp8 x fp8, pure-register operands ----
    f16v S0 = zf16(), S1 = zf16();
    __builtin_amdgcn_s_setprio(1);
#pragma unroll
    for (int cs = 0; cs < 16; ++cs) {
      S0 = __builtin_amdgcn_mfma_f32_32x32x16_fp8_fp8(kf[cs], qf[0][cs], S0, 0, 0, 0);
      S1 = __builtin_amdgcn_mfma_f32_32x32x16_fp8_fp8(kf[cs], qf[1][cs], S1, 0, 0, 0);
    }
    __builtin_amdgcn_s_setprio(0);
    SCHED_FENCE();
    // ---- exp2 + fp8 pack + P write. key = w*32 + 8j + 4lh + (0..3), row = rg*32+l31 ----
    unsigned char* Pw = Ps[t & 1] + (w * 4) * 512 + l31 * 8 + lh * 4;
#pragma unroll
    for (int j = 0; j < 4; ++j) {
      float a0 = EXP2(S0[4 * j + 0]), a1 = EXP2(S0[4 * j + 1]);
      float a2 = EXP2(S0[4 * j + 2]), a3 = EXP2(S0[4 * j + 3]);
      ls0 += (a0 + a1) + (a2 + a3);
      unsigned p0 = (unsigned)__builtin_amdgcn_cvt_pk_fp8_f32(a0, a1, 0, false);
      p0 = (unsigned)__builtin_amdgcn_cvt_pk_fp8_f32(a2, a3, (int)p0, true);
      *(unsigned*)(Pw + j * 512) = p0;
      float c0 = EXP2(S1[4 * j + 0]), c1 = EXP2(S1[4 * j + 1]);
      float c2 = EXP2(S1[4 * j + 2]), c3 = EXP2(S1[4 * j + 3]);
      ls1 += (c0 + c1) + (c2 + c3);
      unsigned p1 = (unsigned)__builtin_amdgcn_cvt_pk_fp8_f32(c0, c1, 0, false);
      p1 = (unsigned)__builtin_amdgcn_cvt_pk_fp8_f32(c2, c3, (int)p1, true);
      *(unsigned*)(Pw + j * 512 + 256) = p1;
    }
    __syncthreads();   // P visible; vf landed (issued before S)
    // ---- kf prefetch for NEXT chunk (t=15 read is benign OOB within kB slack) ----
    kp += 65536;
#pragma unroll
    for (int cs = 0; cs < 16; ++cs) kf[cs] = *(const i64f*)(kp + cs * 512);
    SCHED_FENCE();
    // ---- PV phase: fp8 MFMA; this wave's 32 channels, all 256 keys ----
    const unsigned char* Pr = Ps[t & 1] + (size_t)lh * 512 + l31 * 8;
    __builtin_amdgcn_s_setprio(1);
#pragma unroll
    for (int ks = 0; ks < 16; ++ks) {
      i64f p0 = *(const i64f*)(Pr + ks * 1024);
      i64f p1 = *(const i64f*)(Pr + ks * 1024 + 256);
      O0 = __builtin_amdgcn_mfma_f32_32x32x16_fp8_fp8(vf[ks], p0, O0, 0, 0, 0);
      O1 = __builtin_amdgcn_mfma_f32_32x32x16_fp8_fp8(vf[ks], p1, O1, 0, 0, 0);
    }
    __builtin_amdgcn_s_setprio(0);
    vp += 8192;
  }

  // ---- wp A-frag prefetch (registers free now; lands under the reductions) ----
  s8v wf[16];
#pragma unroll
  for (int cs = 0; cs < 16; ++cs)
    wf[cs] = *(const s8v*)(wpb + (size_t)(w * 32 + l31) * 256 + cs * 16 + lh * 8);
  SCHED_FENCE();

  // lsum: lane has sum over its 16 keys/chunk; partner lane (l^32) has the other 16
  ls0 += __shfl_xor(ls0, 32);
  ls1 += __shfl_xor(ls1, 32);
  if (l < 32) { Lw[w][0][l] = ls0; Lw[w][1][l] = ls1; }
  __syncthreads();
  float s0 = 0.f, s1 = 0.f;
#pragma unroll
  for (int ww = 0; ww < 8; ++ww) { s0 += Lw[ww][0][l31]; s1 += Lw[ww][1][l31]; }
  float rl0 = 1.f / s0, rl1 = 1.f / s1;

  // ---- normalize + write attn-out tile to LDS (bf16 16x16 B-frag, tile-local) ----
#pragma unroll
  for (int jj = 0; jj < 4; ++jj) {
    ushort4 pk;
    pk.x = f2bf(O0[4 * jj + 0] * rl0); pk.y = f2bf(O0[4 * jj + 1] * rl0);
    pk.z = f2bf(O0[4 * jj + 2] * rl0); pk.w = f2bf(O0[4 * jj + 3] * rl0);
    int f0 = ((l31 >> 4) * 32 + w * 4 + jj) * 128 + (l31 & 15) * 8 + lh * 4;
    *(ushort4*)(aS + f0) = pk;
    pk.x = f2bf(O1[4 * jj + 0] * rl1); pk.y = f2bf(O1[4 * jj + 1] * rl1);
    pk.z = f2bf(O1[4 * jj + 2] * rl1); pk.w = f2bf(O1[4 * jj + 3] * rl1);
    int f1 = ((2 + (l31 >> 4)) * 32 + w * 4 + jj) * 128 + (l31 & 15) * 8 + lh * 4;
    *(ushort4*)(aS + f1) = pk;
  }
  __syncthreads();   // aS visible

  // ---- projection GEMM: out[o][n] = sum_c wp[o][c] * a[c][n] ----
  f16v OP0 = zf16(), OP1 = zf16();
#pragma unroll
  for (int cs = 0; cs < 16; ++cs) {
    s8v pa0 = *(const s8v*)(aS + ((0 + (l31 >> 4)) * 32 + cs * 2 + lh) * 128 + (l31 & 15) * 8);
    s8v pa1 = *(const s8v*)(aS + ((2 + (l31 >> 4)) * 32 + cs * 2 + lh) * 128 + (l31 & 15) * 8);
    OP0 = __builtin_amdgcn_mfma_f32_32x32x16_bf16(wf[cs], pa0, OP0, 0, 0, 0);
    OP1 = __builtin_amdgcn_mfma_f32_32x32x16_bf16(wf[cs], pa1, OP1, 0, 0, 0);
  }

  // ---- epilogue: out = x + proj + bp ----
#pragma unroll
  for (int r = 0; r < 16; ++r) {
    int o_ = w * 32 + (r & 3) + 8 * (r >> 2) + 4 * lh;
    float bpv = bp[o_];
    size_t ix = ((size_t)b * C_ + o_) * N_ + i0 + l31;
    out[ix]      = x[ix]      + OP0[r] + bpv;
    out[ix + 32] = x[ix + 32] + OP1[r] + bpv;
  }
}

extern "C" void kernel_launch(void* const* d_in, const int* in_sizes, int n_in,
                              void* d_out, int out_size, void* d_ws, size_t ws_size,
                              hipStream_t stream) {
  const float* x     = (const float*)d_in[0];
  const float* gamma = (const float*)d_in[1];
  const float* beta  = (const float*)d_in[2];
  const float* wq    = (const float*)d_in[3];
  const float* bq    = (const float*)d_in[4];
  const float* wk    = (const float*)d_in[5];
  const float* bk    = (const float*)d_in[6];
  const float* wv    = (const float*)d_in[7];
  const float* bv    = (const float*)d_in[8];
  const float* wp    = (const float*)d_in[9];
  const float* bp    = (const float*)d_in[10];
  float* out = (float*)d_out;

  char* ws = (char*)d_ws;
  float* mean = (float*)ws; ws += 1024;
  float* rstd = (float*)ws; ws += 1024;
  float* beq  = (float*)ws; ws += 1024;
  float* bek  = (float*)ws; ws += 1024;
  float* bev  = (float*)ws; ws += 1024;
  unsigned short* wqb = (unsigned short*)ws; ws += C_ * C_ * 2;
  unsigned short* wkb = (unsigned short*)ws; ws += C_ * C_ * 2;
  unsigned short* wvb = (unsigned short*)ws; ws += C_ * C_ * 2;
  unsigned short* wpb = (unsigned short*)ws; ws += C_ * C_ * 2;
  // fp8 q/k/v occupy half their regions; slack absorbs the benign OOB prefetch
  unsigned char* qB = (unsigned char*)ws; ws += (size_t)B_ * N_ * C_ * 2;
  unsigned char* kB = (unsigned char*)ws; ws += (size_t)B_ * N_ * C_ * 2;
  unsigned char* vB = (unsigned char*)ws; ws += (size_t)B_ * N_ * C_ * 2;

  hipLaunchKernelGGL(bn_stats, dim3(C_), dim3(256), 0, stream, x, mean, rstd);
  hipLaunchKernelGGL(prep, dim3(C_), dim3(256), 0, stream,
                     wq, bq, wk, bk, wv, bv, wp, gamma, beta, mean, rstd,
                     wqb, wkb, wvb, wpb, beq, bek, bev);
  hipLaunchKernelGGL(qkv, dim3(N_ / 64, 1, B_), dim3(256), 0, stream,
                     x, wqb, wkb, wvb, beq, bek, bev, qB, kB, vB);
  hipLaunchKernelGGL(attn, dim3(256), dim3(512), 0, stream,
                     qB, kB, vB, wpb, bp, x, out);
}

// Round 17
// 175.110 us; speedup vs baseline: 1.0349x; 1.0349x over previous
//
#include <hip/hip_runtime.h>
#include <cstdint>
#include <cstddef>

#define B_ 4
#define C_ 256
#define N_ 4096

typedef __attribute__((ext_vector_type(8))) short s8v;    // 8 bf16 (4 VGPRs) MFMA A/B frag
typedef __attribute__((ext_vector_type(4))) float f4v;    // 16x16 MFMA C/D frag
typedef __attribute__((ext_vector_type(16))) float f16v;  // 32x32 MFMA C/D frag
typedef long long i64f;                                   // 8 fp8 (2 VGPRs) MFMA A/B frag

#if defined(__has_builtin)
#if __has_builtin(__builtin_amdgcn_exp2f)
#define EXP2(x) __builtin_amdgcn_exp2f(x)
#endif
#endif
#ifndef EXP2
#define EXP2(x) exp2f(x)
#endif

// scheduling fence: no instruction may be reordered across (pins prefetch issue)
#define SCHED_FENCE() __builtin_amdgcn_sched_barrier(0)

__device__ __forceinline__ unsigned short f2bf(float f) {
  unsigned int u = __builtin_bit_cast(unsigned int, f);
  return (unsigned short)((u + 0x7FFFu + ((u >> 16) & 1u)) >> 16);  // RNE
}

__device__ __forceinline__ float bf2f(unsigned short u) {
  return __builtin_bit_cast(float, (unsigned)u << 16);
}

__device__ __forceinline__ f16v zf16() {
  f16v z;
#pragma unroll
  for (int i = 0; i < 16; ++i) z[i] = 0.f;
  return z;
}

// Layouts:
//  16x16 B-frag blocked bf16 (aS LDS tile): flat = ((n>>4)*32 + (c>>3))*128 + (n&15)*8 + (c&7)
//  qB/kB FP8 e4m3 (32x32x16 fp8 frags, BYTE units): byte = frag_idx*512 + l*8
//    q frag_idx = ((b*128 + n32)*16 + cs) ; k frag_idx = ((b*128 + kg)*16 + cs)
//  vB FP8 e4m3 (BYTE units): byte = (((b*8 + cg)*256 + ks)*64 + l)*8 + e
//  P LDS fp8 (64 rows, 2 rg): byte = k8*512 + l31*8 + klow (+256 for rg=1)
//  NOTE: sqrt(C^-0.5 * log2e) folded into BOTH wq and wk (fp8 dynamic range).

// ---------------- K1: BatchNorm statistics ----------------
__global__ __launch_bounds__(256) void bn_stats(const float* __restrict__ x,
                                                float* __restrict__ mean,
                                                float* __restrict__ rstd) {
  int c = blockIdx.x, t = threadIdx.x;
  float s = 0.f, s2 = 0.f;
  for (int b = 0; b < B_; ++b) {
    const float* p = x + ((size_t)b * C_ + c) * N_;
    for (int n = t * 4; n < N_; n += 1024) {
      float4 v = *(const float4*)(p + n);
      s += (v.x + v.y) + (v.z + v.w);
      s2 += (v.x * v.x + v.y * v.y) + (v.z * v.z + v.w * v.w);
    }
  }
  __shared__ float rs[256], rs2[256];
  rs[t] = s; rs2[t] = s2; __syncthreads();
  for (int off = 128; off > 0; off >>= 1) {
    if (t < off) { rs[t] += rs[t + off]; rs2[t] += rs2[t + off]; }
    __syncthreads();
  }
  if (t == 0) {
    float m = rs[0] * (1.f / 16384.f);
    float v = rs2[0] * (1.f / 16384.f) - m * m;
    mean[c] = m; rstd[c] = rsqrtf(v + 1e-5f);
  }
}

// ---------------- K2: fold BN + split QK scale into weights ----------------
__global__ __launch_bounds__(256) void prep(
    const float* __restrict__ wq, const float* __restrict__ bq,
    const float* __restrict__ wk, const float* __restrict__ bk,
    const float* __restrict__ wv, const float* __restrict__ bv,
    const float* __restrict__ wp,
    const float* __restrict__ gamma, const float* __restrict__ beta,
    const float* __restrict__ mean, const float* __restrict__ rstd,
    unsigned short* __restrict__ wqb, unsigned short* __restrict__ wkb,
    unsigned short* __restrict__ wvb, unsigned short* __restrict__ wpb,
    float* __restrict__ beq, float* __restrict__ bek, float* __restrict__ bev) {
  const float SQ = 0.300280605f;   // sqrt(C^-0.5 * log2(e)); applied to BOTH q and k
  int o = blockIdx.x, c = threadIdx.x;
  float a = gamma[c] * rstd[c];
  float d = beta[c] - mean[c] * a;
  float wqv = wq[o * C_ + c], wkv = wk[o * C_ + c], wvv = wv[o * C_ + c];
  wqb[o * C_ + c] = f2bf(wqv * a * SQ);
  wkb[o * C_ + c] = f2bf(wkv * a * SQ);
  wvb[o * C_ + c] = f2bf(wvv * a);
  wpb[o * C_ + c] = f2bf(wp[o * C_ + c]);
  __shared__ float r0[256], r1[256], r2[256];
  r0[c] = wqv * d; r1[c] = wkv * d; r2[c] = wvv * d; __syncthreads();
  for (int off = 128; off > 0; off >>= 1) {
    if (c < off) { r0[c] += r0[c + off]; r1[c] += r1[c + off]; r2[c] += r2[c + off]; }
    __syncthreads();
  }
  if (c == 0) {
    beq[o] = (bq[o] + r0[0]) * SQ;
    bek[o] = (bk[o] + r1[0]) * SQ;
    bev[o] = bv[o] + r2[0];
  }
}

// ---------------- K3: fused x-convert + QKV GEMM — stage once, 4 PARALLEL oblk groups ----------------
// r16's serial-oblk version (256 blk x 256 thr) lost parallelism: 1 block/CU at
// 4 waves, 26 serialized barriers. Fix: 1024 threads = 16 waves = 4 groups of 4;
// x staged ONCE cooperatively; group og handles oblk=og CONCURRENTLY (own 9 KB
// repack buffer Lr[og]; barrier sequences align across groups). x traffic stays
// /4 vs r14 AND 16 waves/CU hide LDS/L2 latency. LDS 70.7 KB.
__global__ __launch_bounds__(1024) void qkv(
    const float* __restrict__ x,
    const unsigned short* __restrict__ wqb, const unsigned short* __restrict__ wkb,
    const unsigned short* __restrict__ wvb,
    const float* __restrict__ beq, const float* __restrict__ bek,
    const float* __restrict__ bev,
    unsigned char* __restrict__ qB, unsigned char* __restrict__ kB,
    unsigned char* __restrict__ vB) {
  int b = blockIdx.z, n0 = blockIdx.x * 64;
  int tid = threadIdx.x;
  int w16 = tid >> 6, l = tid & 63, quad = l >> 4, lq = l & 15;
  int og = w16 >> 2, wl = w16 & 3;     // oblk group 0..3, wave-in-group 0..3
  int lt = wl * 64 + l;                // 0..255 within group

  __shared__ unsigned short Ls[64][264];     // 33.8 KB x tile [n][c] — persistent
  __shared__ unsigned short Lr[4][64][72];   // 4 x 9.2 KB per-group repack buffers

  // ---- stage x -> Ls (ONCE; wave w16 stages channels [w16*16, w16*16+16)) ----
  {
    const float* xp = x + ((size_t)b * C_ + w16 * 16) * N_ + n0 + l;
#pragma unroll
    for (int i = 0; i < 8; ++i) {
      float f0 = xp[(size_t)(2 * i) * N_];
      float f1 = xp[(size_t)(2 * i + 1) * N_];
      unsigned pk = (unsigned)f2bf(f0) | ((unsigned)f2bf(f1) << 16);
      *(unsigned*)(&Ls[l][w16 * 16 + 2 * i]) = pk;
    }
  }
  __syncthreads();

  int obase = og * 64;
  int orow = obase + wl * 16 + lq;

  f4v aq[4], ak[4], av[4];
#pragma unroll
  for (int nt = 0; nt < 4; ++nt) {
    aq[nt] = (f4v){0.f, 0.f, 0.f, 0.f};
    ak[nt] = (f4v){0.f, 0.f, 0.f, 0.f};
    av[nt] = (f4v){0.f, 0.f, 0.f, 0.f};
  }

#pragma unroll
  for (int kk = 0; kk < 8; ++kk) {
    s8v afq = *(const s8v*)(wqb + (size_t)orow * C_ + kk * 32 + quad * 8);
    s8v afk = *(const s8v*)(wkb + (size_t)orow * C_ + kk * 32 + quad * 8);
    s8v afv = *(const s8v*)(wvb + (size_t)orow * C_ + kk * 32 + quad * 8);
#pragma unroll
    for (int nt = 0; nt < 4; ++nt) {
      s8v bf = *(const s8v*)(&Ls[nt * 16 + lq][kk * 32 + quad * 8]);
      aq[nt] = __builtin_amdgcn_mfma_f32_16x16x32_bf16(afq, bf, aq[nt], 0, 0, 0);
      ak[nt] = __builtin_amdgcn_mfma_f32_16x16x32_bf16(afk, bf, ak[nt], 0, 0, 0);
      av[nt] = __builtin_amdgcn_mfma_f32_16x16x32_bf16(afv, bf, av[nt], 0, 0, 0);
    }
  }

  // pass 1: q -> qB ; pass 2: k -> kB  (stage [n][c] bf16 in Lr[og]; gather; cvt FP8)
  for (int pass = 0; pass < 2; ++pass) {
    const f4v* acc = (pass == 0) ? aq : ak;
    const float* BE = (pass == 0) ? beq : bek;
    int ob4 = obase + wl * 16 + quad * 4;
    float b0 = BE[ob4], b1 = BE[ob4 + 1], b2 = BE[ob4 + 2], b3 = BE[ob4 + 3];
    __syncthreads();   // Lr free (previous pass gathers done, all groups aligned)
#pragma unroll
    for (int nt = 0; nt < 4; ++nt) {
      unsigned lo = (unsigned)f2bf(acc[nt][0] + b0) | ((unsigned)f2bf(acc[nt][1] + b1) << 16);
      unsigned hi = (unsigned)f2bf(acc[nt][2] + b2) | ((unsigned)f2bf(acc[nt][3] + b3) << 16);
      uint2 pr; pr.x = lo; pr.y = hi;
      *(uint2*)(&Lr[og][nt * 16 + lq][wl * 16 + quad * 4]) = pr;
    }
    __syncthreads();
    {
      unsigned char* dp = (pass == 0) ? qB : kB;
#pragma unroll
      for (int ii = 0; ii < 2; ++ii) {
        int i = lt + ii * 256;
        int g = i >> 8, cs = (i >> 6) & 3, ll = i & 63;
        s8v vv = *(const s8v*)(&Lr[og][g * 32 + (ll & 31)][cs * 16 + ((ll >> 5) << 3)]);
        unsigned w0 = (unsigned)__builtin_amdgcn_cvt_pk_fp8_f32(
            bf2f((unsigned short)vv[0]), bf2f((unsigned short)vv[1]), 0, false);
        w0 = (unsigned)__builtin_amdgcn_cvt_pk_fp8_f32(
            bf2f((unsigned short)vv[2]), bf2f((unsigned short)vv[3]), (int)w0, true);
        unsigned w1 = (unsigned)__builtin_amdgcn_cvt_pk_fp8_f32(
            bf2f((unsigned short)vv[4]), bf2f((unsigned short)vv[5]), 0, false);
        w1 = (unsigned)__builtin_amdgcn_cvt_pk_fp8_f32(
            bf2f((unsigned short)vv[6]), bf2f((unsigned short)vv[7]), (int)w1, true);
        uint2 pr; pr.x = w0; pr.y = w1;
        size_t dst = ((((size_t)b * 128 + (n0 >> 5) + g) * 16 + (obase >> 4) + cs) * 64 + ll) * 8;
        *(uint2*)(dp + dst) = pr;
      }
    }
  }

  // pass 3: v (stage [c][n] bf16 in Lr[og]; gather 32x32 A-frag; cvt FP8)
  __syncthreads();   // Lr free (k-pass gathers done)
#pragma unroll
  for (int nt = 0; nt < 4; ++nt)
#pragma unroll
    for (int r = 0; r < 4; ++r) {
      int o_ = obase + wl * 16 + quad * 4 + r;
      Lr[og][wl * 16 + quad * 4 + r][nt * 16 + lq] = f2bf(av[nt][r] + bev[o_]);
    }
  __syncthreads();
  {
#pragma unroll
    for (int ii = 0; ii < 2; ++ii) {
      int i = lt + ii * 256;
      int g = i >> 8, ks = (i >> 6) & 3, ll = i & 63;
      s8v vv = *(const s8v*)(&Lr[og][g * 32 + (ll & 31)][ks * 16 + ((ll >> 5) << 3)]);
      unsigned w0 = (unsigned)__builtin_amdgcn_cvt_pk_fp8_f32(
          bf2f((unsigned short)vv[0]), bf2f((unsigned short)vv[1]), 0, false);
      w0 = (unsigned)__builtin_amdgcn_cvt_pk_fp8_f32(
          bf2f((unsigned short)vv[2]), bf2f((unsigned short)vv[3]), (int)w0, true);
      unsigned w1 = (unsigned)__builtin_amdgcn_cvt_pk_fp8_f32(
          bf2f((unsigned short)vv[4]), bf2f((unsigned short)vv[5]), 0, false);
      w1 = (unsigned)__builtin_amdgcn_cvt_pk_fp8_f32(
          bf2f((unsigned short)vv[6]), bf2f((unsigned short)vv[7]), (int)w1, true);
      uint2 pr; pr.x = w0; pr.y = w1;
      size_t dst = ((((size_t)b * 8 + (obase >> 5) + g) * 256 + (n0 >> 4) + ks) * 64 + ll) * 8;
      *(uint2*)(vB + dst) = pr;
    }
  }
}

// ---------------- K4: FMHA — full-FP8 operands: Q resident in regs, no Q LDS ----------------
// (byte-identical to the round-14 passing kernel: ~71-72 us, absmax 0.031)
__global__ __launch_bounds__(512, 2) void attn(
    const unsigned char* __restrict__ qB, const unsigned char* __restrict__ kB,
    const unsigned char* __restrict__ vB,
    const unsigned short* __restrict__ wpb, const float* __restrict__ bp,
    const float* __restrict__ x, float* __restrict__ out) {
  int id = blockIdx.x;                       // id&7 = XCD (2 XCDs per batch)
  int b = (id & 7) >> 1;
  int i0 = (((id >> 3) << 1) | (id & 1)) << 6;   // 64 q-rows per block
  int tid = threadIdx.x, w = tid >> 6, l = tid & 63;
  int lh = l >> 5, l31 = l & 31;

  __shared__ unsigned char Ps[2][16384];     // 2 x 16 KB P tiles (fp8)
  __shared__ unsigned short aS[16384];       // 32 KB attn-out tile (bf16, proj input)
  __shared__ float Lw[8][2][32];

  // Q resident in registers: 32 fp8 B-frags (64 VGPR), loaded once from L2.
  i64f qf[2][16];
  {
    const unsigned char* qp = qB + (((size_t)b * 64 + (i0 >> 6)) * 32) * 512 + (size_t)l * 8;
#pragma unroll
    for (int rg = 0; rg < 2; ++rg)
#pragma unroll
      for (int cs = 0; cs < 16; ++cs)
        qf[rg][cs] = *(const i64f*)(qp + (size_t)(rg * 16 + cs) * 512);
  }

  // K (fp8): wave w owns key32-group w of each chunk; advance 8 groups = 65536 B/chunk
  const unsigned char* kp = kB + (((size_t)b * 128 + w) * 16) * 512 + (size_t)l * 8;
  // V (fp8): wave w owns channel-group w; frag ks at +ks*512 B
  const unsigned char* vp = vB + (((size_t)b * 8 + w) * 256) * 512 + (size_t)l * 8;

  // prologue: kf for chunk 0 (fp8: 16 x 8 B = 32 VGPR)
  i64f kf[16];
#pragma unroll
  for (int cs = 0; cs < 16; ++cs) kf[cs] = *(const i64f*)(kp + cs * 512);
  SCHED_FENCE();

  f16v O0 = zf16(), O1 = zf16();   // [rg] channels w*32+chl, rows i0+rg*32+l31
  float ls0 = 0.f, ls1 = 0.f;

  for (int t = 0; t < 16; ++t) {
    // ---- vf prefetch for THIS chunk ----
    i64f vf[16];
#pragma unroll
    for (int ks = 0; ks < 16; ++ks) vf[ks] = *(const i64f*)(vp + ks * 512);
    SCHED_FENCE();
    // ---- S phase: fp8 x fp8, pure-register operands ----
    f16v S0 = zf16(), S1 = zf16();
    __builtin_amdgcn_s_setprio(1);
#pragma unroll
    for (int cs = 0; cs < 16; ++cs) {
      S0 = __builtin_amdgcn_mfma_f32_32x32x16_fp8_fp8(kf[cs], qf[0][cs], S0, 0, 0, 0);
      S1 = __builtin_amdgcn_mfma_f32_32x32x16_fp8_fp8(kf[cs], qf[1][cs], S1, 0, 0, 0);
    }
    __builtin_amdgcn_s_setprio(0);
    SCHED_FENCE();
    // ---- exp2 + fp8 pack + P write. key = w*32 + 8j + 4lh + (0..3), row = rg*32+l31 ----
    unsigned char* Pw = Ps[t & 1] + (w * 4) * 512 + l31 * 8 + lh * 4;
#pragma unroll
    for (int j = 0; j < 4; ++j) {
      float a0 = EXP2(S0[4 * j + 0]), a1 = EXP2(S0[4 * j + 1]);
      float a2 = EXP2(S0[4 * j + 2]), a3 = EXP2(S0[4 * j + 3]);
      ls0 += (a0 + a1) + (a2 + a3);
      unsigned p0 = (unsigned)__builtin_amdgcn_cvt_pk_fp8_f32(a0, a1, 0, false);
      p0 = (unsigned)__builtin_amdgcn_cvt_pk_fp8_f32(a2, a3, (int)p0, true);
      *(unsigned*)(Pw + j * 512) = p0;
      float c0 = EXP2(S1[4 * j + 0]), c1 = EXP2(S1[4 * j + 1]);
      float c2 = EXP2(S1[4 * j + 2]), c3 = EXP2(S1[4 * j + 3]);
      ls1 += (c0 + c1) + (c2 + c3);
      unsigned p1 = (unsigned)__builtin_amdgcn_cvt_pk_fp8_f32(c0, c1, 0, false);
      p1 = (unsigned)__builtin_amdgcn_cvt_pk_fp8_f32(c2, c3, (int)p1, true);
      *(unsigned*)(Pw + j * 512 + 256) = p1;
    }
    __syncthreads();   // P visible; vf landed (issued before S)
    // ---- kf prefetch for NEXT chunk (t=15 read is benign OOB within kB slack) ----
    kp += 65536;
#pragma unroll
    for (int cs = 0; cs < 16; ++cs) kf[cs] = *(const i64f*)(kp + cs * 512);
    SCHED_FENCE();
    // ---- PV phase: fp8 MFMA; this wave's 32 channels, all 256 keys ----
    const unsigned char* Pr = Ps[t & 1] + (size_t)lh * 512 + l31 * 8;
    __builtin_amdgcn_s_setprio(1);
#pragma unroll
    for (int ks = 0; ks < 16; ++ks) {
      i64f p0 = *(const i64f*)(Pr + ks * 1024);
      i64f p1 = *(const i64f*)(Pr + ks * 1024 + 256);
      O0 = __builtin_amdgcn_mfma_f32_32x32x16_fp8_fp8(vf[ks], p0, O0, 0, 0, 0);
      O1 = __builtin_amdgcn_mfma_f32_32x32x16_fp8_fp8(vf[ks], p1, O1, 0, 0, 0);
    }
    __builtin_amdgcn_s_setprio(0);
    vp += 8192;
  }

  // ---- wp A-frag prefetch (registers free now; lands under the reductions) ----
  s8v wf[16];
#pragma unroll
  for (int cs = 0; cs < 16; ++cs)
    wf[cs] = *(const s8v*)(wpb + (size_t)(w * 32 + l31) * 256 + cs * 16 + lh * 8);
  SCHED_FENCE();

  // lsum: lane has sum over its 16 keys/chunk; partner lane (l^32) has the other 16
  ls0 += __shfl_xor(ls0, 32);
  ls1 += __shfl_xor(ls1, 32);
  if (l < 32) { Lw[w][0][l] = ls0; Lw[w][1][l] = ls1; }
  __syncthreads();
  float s0 = 0.f, s1 = 0.f;
#pragma unroll
  for (int ww = 0; ww < 8; ++ww) { s0 += Lw[ww][0][l31]; s1 += Lw[ww][1][l31]; }
  float rl0 = 1.f / s0, rl1 = 1.f / s1;

  // ---- normalize + write attn-out tile to LDS (bf16 16x16 B-frag, tile-local) ----
#pragma unroll
  for (int jj = 0; jj < 4; ++jj) {
    ushort4 pk;
    pk.x = f2bf(O0[4 * jj + 0] * rl0); pk.y = f2bf(O0[4 * jj + 1] * rl0);
    pk.z = f2bf(O0[4 * jj + 2] * rl0); pk.w = f2bf(O0[4 * jj + 3] * rl0);
    int f0 = ((l31 >> 4) * 32 + w * 4 + jj) * 128 + (l31 & 15) * 8 + lh * 4;
    *(ushort4*)(aS + f0) = pk;
    pk.x = f2bf(O1[4 * jj + 0] * rl1); pk.y = f2bf(O1[4 * jj + 1] * rl1);
    pk.z = f2bf(O1[4 * jj + 2] * rl1); pk.w = f2bf(O1[4 * jj + 3] * rl1);
    int f1 = ((2 + (l31 >> 4)) * 32 + w * 4 + jj) * 128 + (l31 & 15) * 8 + lh * 4;
    *(ushort4*)(aS + f1) = pk;
  }
  __syncthreads();   // aS visible

  // ---- projection GEMM: out[o][n] = sum_c wp[o][c] * a[c][n] ----
  f16v OP0 = zf16(), OP1 = zf16();
#pragma unroll
  for (int cs = 0; cs < 16; ++cs) {
    s8v pa0 = *(const s8v*)(aS + ((0 + (l31 >> 4)) * 32 + cs * 2 + lh) * 128 + (l31 & 15) * 8);
    s8v pa1 = *(const s8v*)(aS + ((2 + (l31 >> 4)) * 32 + cs * 2 + lh) * 128 + (l31 & 15) * 8);
    OP0 = __builtin_amdgcn_mfma_f32_32x32x16_bf16(wf[cs], pa0, OP0, 0, 0, 0);
    OP1 = __builtin_amdgcn_mfma_f32_32x32x16_bf16(wf[cs], pa1, OP1, 0, 0, 0);
  }

  // ---- epilogue: out = x + proj + bp ----
#pragma unroll
  for (int r = 0; r < 16; ++r) {
    int o_ = w * 32 + (r & 3) + 8 * (r >> 2) + 4 * lh;
    float bpv = bp[o_];
    size_t ix = ((size_t)b * C_ + o_) * N_ + i0 + l31;
    out[ix]      = x[ix]      + OP0[r] + bpv;
    out[ix + 32] = x[ix + 32] + OP1[r] + bpv;
  }
}

extern "C" void kernel_launch(void* const* d_in, const int* in_sizes, int n_in,
                              void* d_out, int out_size, void* d_ws, size_t ws_size,
                              hipStream_t stream) {
  const float* x     = (const float*)d_in[0];
  const float* gamma = (const float*)d_in[1];
  const float* beta  = (const float*)d_in[2];
  const float* wq    = (const float*)d_in[3];
  const float* bq    = (const float*)d_in[4];
  const float* wk    = (const float*)d_in[5];
  const float* bk    = (const float*)d_in[6];
  const float* wv    = (const float*)d_in[7];
  const float* bv    = (const float*)d_in[8];
  const float* wp    = (const float*)d_in[9];
  const float* bp    = (const float*)d_in[10];
  float* out = (float*)d_out;

  char* ws = (char*)d_ws;
  float* mean = (float*)ws; ws += 1024;
  float* rstd = (float*)ws; ws += 1024;
  float* beq  = (float*)ws; ws += 1024;
  float* bek  = (float*)ws; ws += 1024;
  float* bev  = (float*)ws; ws += 1024;
  unsigned short* wqb = (unsigned short*)ws; ws += C_ * C_ * 2;
  unsigned short* wkb = (unsigned short*)ws; ws += C_ * C_ * 2;
  unsigned short* wvb = (unsigned short*)ws; ws += C_ * C_ * 2;
  unsigned short* wpb = (unsigned short*)ws; ws += C_ * C_ * 2;
  // fp8 q/k/v occupy half their regions; slack absorbs the benign OOB prefetch
  unsigned char* qB = (unsigned char*)ws; ws += (size_t)B_ * N_ * C_ * 2;
  unsigned char* kB = (unsigned char*)ws; ws += (size_t)B_ * N_ * C_ * 2;
  unsigned char* vB = (unsigned char*)ws; ws += (size_t)B_ * N_ * C_ * 2;

  hipLaunchKernelGGL(bn_stats, dim3(C_), dim3(256), 0, stream, x, mean, rstd);
  hipLaunchKernelGGL(prep, dim3(C_), dim3(256), 0, stream,
                     wq, bq, wk, bk, wv, bv, wp, gamma, beta, mean, rstd,
                     wqb, wkb, wvb, wpb, beq, bek, bev);
  hipLaunchKernelGGL(qkv, dim3(N_ / 64, 1, B_), dim3(1024), 0, stream,
                     x, wqb, wkb, wvb, beq, bek, bev, qB, kB, vB);
  hipLaunchKernelGGL(attn, dim3(256), dim3(512), 0, stream,
                     qB, kB, vB, wpb, bp, x, out);
}